// Round 2
// baseline (185.855 us; speedup 1.0000x reference)
//
#include <hip/hip_runtime.h>
#include <math.h>

// RandomMicEQ: cascade of 3 biquads (EQ -> LP -> HP), each stage's output
// clamped to [-1,1] before the next stage; recursion history is UNCLAMPED
// (matches jax ref: clip after scan, carry unclamped).
//
// Overlap-save chunking: each thread computes an L-sample output chunk,
// running the fused cascade from zero state W samples early. Slowest pole is
// HP@300Hz, r=0.9702 -> transient at W=384 ~ 1e-6, far below the 7.7e-3
// threshold (measured absmax 1.95e-3 is fp32 roundoff, W-independent).
//
// R2: L 256->128 (1723 waves = 1.7/SIMD, was 0.84) + 4-deep float4 prefetch
// to cover load latency. R1 was latency-bound: VALUBusy 20%, HBM 23%.

struct BQ { float b0, b1, b2, a1, a2; };

#define L_CHUNK 128
#define W_WARM  384
#define PF      4      // prefetch depth (float4 slots in flight)

__global__ __launch_bounds__(64) void biquad3_kernel(
    const float* __restrict__ x, float* __restrict__ out,
    int T, int chunksPerRow, int nThreads,
    BQ F1, BQ F2, BQ F3)
{
    int tid = blockIdx.x * blockDim.x + threadIdx.x;
    if (tid >= nThreads) return;
    int row = tid / chunksPerRow;
    int c   = tid - row * chunksPerRow;

    int t0    = c * L_CHUNK;          // first output sample of this chunk
    int begin = t0 - W_WARM;          // warm-up start (zero initial state)
    if (begin < 0) begin = 0;
    int end   = t0 + L_CHUNK;
    if (end > T) end = T;
    // begin/end/t0 are multiples of 4; row base is 16B aligned.

    const float* xr = x   + (long long)row * T;
    float*       yr = out + (long long)row * T;

    // filter states (direct-form I per stage)
    float x1=0.f, x2=0.f, y1=0.f, y2=0.f;   // stage 1 (EQ)
    float u1=0.f, u2=0.f, v1=0.f, v2=0.f;   // stage 2 (LP)
    float p1=0.f, p2=0.f, q1=0.f, q2=0.f;   // stage 3 (HP)

    auto step = [&](float xt) -> float {
        float f = F1.b0*xt + F1.b1*x1 + F1.b2*x2;
        float y = (f - F1.a2*y2) - F1.a1*y1;
        x2 = x1; x1 = xt; y2 = y1; y1 = y;
        float u = fminf(fmaxf(y, -1.f), 1.f);

        float g = F2.b0*u + F2.b1*u1 + F2.b2*u2;
        float v = (g - F2.a2*v2) - F2.a1*v1;
        u2 = u1; u1 = u; v2 = v1; v1 = v;
        float p = fminf(fmaxf(v, -1.f), 1.f);

        float h = F3.b0*p + F3.b1*p1 + F3.b2*p2;
        float q = (h - F3.a2*q2) - F3.a1*q1;
        p2 = p1; p1 = p; q2 = q1; q1 = q;
        return fminf(fmaxf(q, -1.f), 1.f);
    };

    // PF-deep rotating prefetch buffer of float4s
    float4 buf[PF];
#pragma unroll
    for (int j = 0; j < PF; ++j) {
        int tj = begin + 4 * j;
        buf[j] = (tj < end) ? *(const float4*)(xr + tj)
                            : make_float4(0.f, 0.f, 0.f, 0.f);
    }

#pragma unroll 4
    for (int t = begin; t < end; t += 4) {
        float4 cur = buf[0];
        buf[0] = buf[1]; buf[1] = buf[2]; buf[2] = buf[3];
        int tp = t + 4 * PF;
        if (tp < end) buf[PF - 1] = *(const float4*)(xr + tp);

        float o0 = step(cur.x);
        float o1 = step(cur.y);
        float o2 = step(cur.z);
        float o3 = step(cur.w);
        if (t >= t0) {
            *(float4*)(yr + t) = make_float4(o0, o1, o2, o3);
        }
    }
}

// ---- host-side coefficient computation (double, matching numpy refs) ----

static BQ norm_ba(double b0, double b1, double b2, double a0, double a1, double a2) {
    BQ r;
    r.b0 = (float)(b0 / a0); r.b1 = (float)(b1 / a0); r.b2 = (float)(b2 / a0);
    r.a1 = (float)(a1 / a0); r.a2 = (float)(a2 / a0);
    return r;
}

static BQ make_eq(double f0, double gain_db, double Q) {
    const double SR = 44100.0;
    double w0 = 2.0 * M_PI * f0 / SR;
    double alpha = sin(w0) / (2.0 * Q);
    double A = pow(10.0, gain_db / 40.0);
    return norm_ba(1.0 + alpha * A, -2.0 * cos(w0), 1.0 - alpha * A,
                   1.0 + alpha / A, -2.0 * cos(w0), 1.0 - alpha / A);
}

static BQ make_lp(double cutoff, double Q) {
    const double SR = 44100.0;
    double w0 = 2.0 * M_PI * cutoff / SR;
    double alpha = sin(w0) / (2.0 * Q);
    double c = cos(w0);
    return norm_ba((1.0 - c) / 2.0, 1.0 - c, (1.0 - c) / 2.0,
                   1.0 + alpha, -2.0 * c, 1.0 - alpha);
}

static BQ make_hp(double cutoff, double Q) {
    const double SR = 44100.0;
    double w0 = 2.0 * M_PI * cutoff / SR;
    double alpha = sin(w0) / (2.0 * Q);
    double c = cos(w0);
    return norm_ba((1.0 + c) / 2.0, -(1.0 + c), (1.0 + c) / 2.0,
                   1.0 + alpha, -2.0 * c, 1.0 - alpha);
}

extern "C" void kernel_launch(void* const* d_in, const int* in_sizes, int n_in,
                              void* d_out, int out_size, void* d_ws, size_t ws_size,
                              hipStream_t stream) {
    const float* x = (const float*)d_in[0];
    float* out = (float*)d_out;

    const int T = 441000;                 // time length (fixed by reference)
    int total = in_sizes[0];
    int B = total / T;                    // 32

    int chunksPerRow = (T + L_CHUNK - 1) / L_CHUNK;   // 3446
    int nThreads = B * chunksPerRow;                  // 110272

    BQ f1 = make_eq(1000.0, 6.0, 1.0);
    BQ f2 = make_lp(8000.0, 0.7071067811865476);
    BQ f3 = make_hp(300.0, 0.7071067811865476);

    int block = 64;   // 1 wave/block -> 1723 blocks spread across 256 CUs
    int grid = (nThreads + block - 1) / block;
    hipLaunchKernelGGL(biquad3_kernel, dim3(grid), dim3(block), 0, stream,
                       x, out, T, chunksPerRow, nThreads, f1, f2, f3);
}

// Round 3
// 141.194 us; speedup vs baseline: 1.3163x; 1.3163x over previous
//
#include <hip/hip_runtime.h>
#include <math.h>

// RandomMicEQ: cascade of 3 biquads (EQ -> LP -> HP), stage outputs clamped
// to [-1,1], recursion history UNCLAMPED (matches jax ref).
//
// Overlap-save chunking: thread = one L-sample chunk, run from zero state
// W samples early. Dominant pole r=0.9702 (HP@300Hz): transient at W=256
// ~ 1.3e-4, well under the 7.7e-3 threshold (measured absmax 1.95e-3 is
// fp32 roundoff, W-independent).
//
// R3: fix scattered-write RMW amplification (R2: WRITE_SIZE 164MB vs 56MB
// ideal, BW stuck at 2.6TB/s). One wave = 64 consecutive chunks = contiguous
// 32KB output span. Output staged in LDS in 32-sample pieces (pitch 33 ->
// 2-way bank aliasing = free), then wave-cooperatively stored as fully
// covered 128B-aligned segments. W 384->256 cuts redundancy 4x->3x.

struct BQ { float b0, b1, b2, a1, a2; };

#define L_CHUNK 128
#define W_WARM  256
#define PIECE   32
#define NPIECE  (L_CHUNK / PIECE)   // 4
#define NCH     64                  // chunks per block (= block size)
#define PITCH   33                  // dword pitch per chunk in LDS (pad +1)
#define PF      4                   // float4 prefetch depth

__global__ __launch_bounds__(64) void biquad3_kernel(
    const float* __restrict__ x, float* __restrict__ out,
    int T, int chunksPerRow, BQ F1, BQ F2, BQ F3)
{
    __shared__ float lds[2 * NCH * PITCH];   // double-buffered piece staging

    const int lane   = threadIdx.x;
    const int row    = blockIdx.y;
    const int chunk0 = blockIdx.x * NCH;
    const int chunk  = chunk0 + lane;
    const bool alive = chunk < chunksPerRow;

    const float* xr = x   + (size_t)row * T;
    float*       yr = out + (size_t)row * T;

    const int t0 = chunk * L_CHUNK;
    int begin = t0 - W_WARM; if (begin < 0) begin = 0;
    int end   = t0 + L_CHUNK; if (end > T) end = T;
    if (!alive) { begin = 0; end = 0; }

    // direct-form I states for the 3 stages
    float x1=0.f,x2=0.f,y1=0.f,y2=0.f;
    float u1=0.f,u2=0.f,v1=0.f,v2=0.f;
    float p1=0.f,p2=0.f,q1=0.f,q2=0.f;

    // rotating float4 prefetch pipeline over [begin, end)
    float4 buf[PF];
    int tpre = begin;
#pragma unroll
    for (int j = 0; j < PF; ++j) {
        buf[j] = (tpre < end) ? *(const float4*)(xr + tpre)
                              : make_float4(0.f,0.f,0.f,0.f);
        tpre += 4;
    }
    auto nextvec = [&]() -> float4 {
        float4 c = buf[0];
        buf[0] = buf[1]; buf[1] = buf[2]; buf[2] = buf[3];
        if (tpre < end) buf[3] = *(const float4*)(xr + tpre);
        tpre += 4;
        return c;
    };

    auto step = [&](float xt) -> float {
        float f = F1.b0*xt + F1.b1*x1 + F1.b2*x2;
        float y = (f - F1.a2*y2) - F1.a1*y1;
        x2 = x1; x1 = xt; y2 = y1; y1 = y;
        float u = fminf(fmaxf(y, -1.f), 1.f);

        float g = F2.b0*u + F2.b1*u1 + F2.b2*u2;
        float v = (g - F2.a2*v2) - F2.a1*v1;
        u2 = u1; u1 = u; v2 = v1; v1 = v;
        float pp = fminf(fmaxf(v, -1.f), 1.f);

        float h = F3.b0*pp + F3.b1*p1 + F3.b2*p2;
        float q = (h - F3.a2*q2) - F3.a1*q1;
        p2 = p1; p1 = pp; q2 = q1; q1 = q;
        return fminf(fmaxf(q, -1.f), 1.f);
    };

    // ---- warm-up: run cascade, discard output ----
    if (alive) {
        for (int t = begin; t < t0; t += 4) {
            float4 c = nextvec();
            step(c.x); step(c.y); step(c.z); step(c.w);
        }
    }

    // contiguous output span of this block (64 consecutive chunks)
    const int spanBase = chunk0 * L_CHUNK;
    int spanEnd = spanBase + NCH * L_CHUNK;
    if (spanEnd > T) spanEnd = T;

    // ---- output: compute 32-sample pieces into LDS, flush coalesced ----
    for (int p = 0; p < NPIECE; ++p) {
        float* slot = lds + (p & 1) * (NCH * PITCH);
        if (alive) {
            float* myrow = slot + lane * PITCH;
#pragma unroll
            for (int s = 0; s < PIECE; s += 4) {
                float4 c = nextvec();
                myrow[s+0] = step(c.x);
                myrow[s+1] = step(c.y);
                myrow[s+2] = step(c.z);
                myrow[s+3] = step(c.w);
            }
        }
        __syncthreads();   // writes visible wave-wide (1-wave block: cheap)
        // flush: 64 chunks x 32 floats; per instruction 64 lanes cover
        // 8 x 128B contiguous aligned segments -> no partial-line RMW
#pragma unroll
        for (int i = lane * 4; i < NCH * PIECE; i += 64 * 4) {
            int c = i >> 5;           // / PIECE
            int j = i & (PIECE - 1);
            int g = spanBase + c * L_CHUNK + p * PIECE + j;
            if (g < spanEnd) {
                // scalar LDS reads (pitch 33 keeps banks 2-way = free)
                float4 v4 = make_float4(slot[c*PITCH + j],
                                        slot[c*PITCH + j + 1],
                                        slot[c*PITCH + j + 2],
                                        slot[c*PITCH + j + 3]);
                *(float4*)(yr + g) = v4;
            }
        }
        // no WAR barrier needed: LDS double-buffered, block = 1 wave
    }
}

// ---- host-side coefficient computation (double, matching numpy refs) ----

static BQ norm_ba(double b0, double b1, double b2,
                  double a0, double a1, double a2) {
    BQ r;
    r.b0 = (float)(b0/a0); r.b1 = (float)(b1/a0); r.b2 = (float)(b2/a0);
    r.a1 = (float)(a1/a0); r.a2 = (float)(a2/a0);
    return r;
}

static BQ make_eq(double f0, double gain_db, double Q) {
    const double SR = 44100.0;
    double w0 = 2.0 * M_PI * f0 / SR;
    double alpha = sin(w0) / (2.0 * Q);
    double A = pow(10.0, gain_db / 40.0);
    return norm_ba(1.0 + alpha*A, -2.0*cos(w0), 1.0 - alpha*A,
                   1.0 + alpha/A, -2.0*cos(w0), 1.0 - alpha/A);
}

static BQ make_lp(double cutoff, double Q) {
    const double SR = 44100.0;
    double w0 = 2.0 * M_PI * cutoff / SR;
    double alpha = sin(w0) / (2.0 * Q);
    double c = cos(w0);
    return norm_ba((1.0-c)/2.0, 1.0-c, (1.0-c)/2.0,
                   1.0+alpha, -2.0*c, 1.0-alpha);
}

static BQ make_hp(double cutoff, double Q) {
    const double SR = 44100.0;
    double w0 = 2.0 * M_PI * cutoff / SR;
    double alpha = sin(w0) / (2.0 * Q);
    double c = cos(w0);
    return norm_ba((1.0+c)/2.0, -(1.0+c), (1.0+c)/2.0,
                   1.0+alpha, -2.0*c, 1.0-alpha);
}

extern "C" void kernel_launch(void* const* d_in, const int* in_sizes, int n_in,
                              void* d_out, int out_size, void* d_ws, size_t ws_size,
                              hipStream_t stream) {
    const float* x = (const float*)d_in[0];
    float* out = (float*)d_out;

    const int T = 441000;
    int total = in_sizes[0];
    int B = total / T;                                  // 32

    int chunksPerRow = (T + L_CHUNK - 1) / L_CHUNK;     // 3446
    int wavesPerRow  = (chunksPerRow + NCH - 1) / NCH;  // 54

    BQ f1 = make_eq(1000.0, 6.0, 1.0);
    BQ f2 = make_lp(8000.0, 0.7071067811865476);
    BQ f3 = make_hp(300.0, 0.7071067811865476);

    dim3 grid(wavesPerRow, B);
    hipLaunchKernelGGL(biquad3_kernel, grid, dim3(64), 0, stream,
                       x, out, T, chunksPerRow, f1, f2, f3);
}